// Round 8
// baseline (1186.220 us; speedup 1.0000x reference)
//
#include <hip/hip_runtime.h>
#include <stdint.h>

// Problem constants
#define BB 2
#define TT 2048
#define DD 2048
#define HH 16
#define HD 2048     // H*Dk = H*Dv
#define MM 4096     // B*T
#define SCH 16      // scan chunk steps

typedef float f32x4 __attribute__((ext_vector_type(4)));
typedef __bf16 bf16x8 __attribute__((ext_vector_type(8)));
typedef unsigned short u16x4 __attribute__((ext_vector_type(4)));

__device__ __forceinline__ unsigned short f2b(float f) {
  unsigned int u = __float_as_uint(f);
  u += 0x7FFFu + ((u >> 16) & 1u);   // RNE
  return (unsigned short)(u >> 16);
}

__device__ __forceinline__ void async_ld16(const void* g, void* l) {
  typedef __attribute__((address_space(3))) void as3_t;
  typedef const __attribute__((address_space(1))) void as1_t;
  // NOTE: LDS arg must be WAVE-UNIFORM base; HW adds lane*16 itself.
  __builtin_amdgcn_global_load_lds((as1_t*)(uintptr_t)g,
                                   (as3_t*)(unsigned int)(uintptr_t)l, 16, 0, 0);
}

// ---- DPP 16-lane all-reduce (VALU-pipe; avoids ds_swizzle ~120cyc latency) ----
// NOTE (r6 lesson): keep BUILTIN form. Raw-asm v_add_f32_dpp chains violate the
// "VALU write -> DPP read needs 2 wait states" hazard (compiler inserts nops
// only for builtin-generated DPP); r6's asm version silently computed garbage.
template <int CTRL>
__device__ __forceinline__ float dpp_add(float x) {
  int y = __builtin_amdgcn_update_dpp(0, __float_as_int(x), CTRL, 0xF, 0xF, false);
  return x + __int_as_float(y);
}
__device__ __forceinline__ float reduce16(float x) {
  x = dpp_add<0xB1>(x);    // quad_perm [1,0,3,2]  (xor 1)
  x = dpp_add<0x4E>(x);    // quad_perm [2,3,0,1]  (xor 2)
  x = dpp_add<0x124>(x);   // row_ror:4
  x = dpp_add<0x128>(x);   // row_ror:8
  return x;                // all 16 lanes hold the row sum
}

// Three INDEPENDENT 16-lane reduces, stage-interleaved: consecutive DPP ops
// belong to different chains, so the DPP read-after-VALU-write wait states
// are filled by the sibling chains -> runs at issue rate, not latency rate.
__device__ __forceinline__ void reduce16x3(float& a, float& b, float& c) {
  a = dpp_add<0xB1>(a);  b = dpp_add<0xB1>(b);  c = dpp_add<0xB1>(c);
  a = dpp_add<0x4E>(a);  b = dpp_add<0x4E>(b);  c = dpp_add<0x4E>(c);
  a = dpp_add<0x124>(a); b = dpp_add<0x124>(b); c = dpp_add<0x124>(c);
  a = dpp_add<0x128>(a); b = dpp_add<0x128>(b); c = dpp_add<0x128>(c);
}

// ---------------- cast f32 -> bf16 (vectorized x4) ----------------
__global__ __launch_bounds__(256) void cast_f32_bf16(const float* __restrict__ in,
                                                     unsigned short* __restrict__ out,
                                                     int n4) {
  int i = blockIdx.x * 256 + threadIdx.x;
  if (i >= n4) return;
  f32x4 v = *(const f32x4*)(in + (size_t)i * 4);
  u16x4 r;
  #pragma unroll
  for (int j = 0; j < 4; j++) r[j] = f2b(v[j]);
  *(u16x4*)(out + (size_t)i * 4) = r;
}

// ---------------- transpose + cast: in f32 [R,C] -> out bf16 [C,R] ----------------
__global__ __launch_bounds__(256) void transpose_cast(const float* __restrict__ in,
                                                      unsigned short* __restrict__ out,
                                                      int R, int C) {
  __shared__ float tile[32][33];
  int bx = blockIdx.x * 32, by = blockIdx.y * 32;
  int tx = threadIdx.x, ty = threadIdx.y;
  #pragma unroll
  for (int i = 0; i < 32; i += 8)
    tile[ty + i][tx] = in[(size_t)(by + ty + i) * C + bx + tx];
  __syncthreads();
  #pragma unroll
  for (int i = 0; i < 32; i += 8)
    out[(size_t)(bx + ty + i) * R + by + tx] = f2b(tile[tx][ty + i]);
}

// ---------------- bf16 GEMM: C[M,N] f32 = A[M,K] @ Bt[N,K]^T (+bias) ----------------
// Tile remap: XCD c (dispatch id%8) gets a CONTIGUOUS range of tile ids, so the
// 16 N-tiles sharing one A row-panel land on the SAME XCD's L2 (T1). Bijective
// when grid total % 8 == 0 (all our grids: 512/128/32).
__global__ __launch_bounds__(256) void gemm_bf16(const unsigned short* __restrict__ A,
                                                 const unsigned short* __restrict__ Bt,
                                                 float* __restrict__ C,
                                                 const float* __restrict__ bias,
                                                 int M, int N, int K) {
  __shared__ __align__(16) unsigned short As[128 * 32];
  __shared__ __align__(16) unsigned short Bs[128 * 32];
  int tid = threadIdx.x;
  int l = tid & 63, w = tid >> 6;

  int nbx = gridDim.x;
  int tot = nbx * gridDim.y;
  int id = blockIdx.y * nbx + blockIdx.x;
  int nid = id;
  if ((tot & 7) == 0) {
    int per = tot >> 3;
    nid = (id & 7) * per + (id >> 3);
  }
  int row0 = (nid / nbx) * 128, col0 = (nid % nbx) * 128;

  int wm = (w >> 1) * 64, wn = (w & 1) * 64;
  const f32x4 fz = {0.f, 0.f, 0.f, 0.f};
  f32x4 acc[4][4];
  #pragma unroll
  for (int i = 0; i < 4; i++)
    #pragma unroll
    for (int j = 0; j < 4; j++) acc[i][j] = fz;

  int srow = l >> 2, skoff = (l & 3) * 8;
  int quad = l >> 4, mrow = l & 15;

  for (int kt = 0; kt < K; kt += 32) {
    #pragma unroll
    for (int i = 0; i < 2; i++) {
      int c = w * 2 + i;
      const unsigned short* gA = A + (size_t)(row0 + c * 16 + srow) * K + kt + skoff;
      const unsigned short* gB = Bt + (size_t)(col0 + c * 16 + srow) * K + kt + skoff;
      async_ld16(gA, As + c * 512);
      async_ld16(gB, Bs + c * 512);
    }
    __syncthreads();
    bf16x8 af[4], bfr[4];
    #pragma unroll
    for (int i = 0; i < 4; i++)
      af[i] = *(const bf16x8*)(As + (wm + i * 16 + mrow) * 32 + quad * 8);
    #pragma unroll
    for (int j = 0; j < 4; j++)
      bfr[j] = *(const bf16x8*)(Bs + (wn + j * 16 + mrow) * 32 + quad * 8);
    #pragma unroll
    for (int i = 0; i < 4; i++)
      #pragma unroll
      for (int j = 0; j < 4; j++)
        acc[i][j] = __builtin_amdgcn_mfma_f32_16x16x32_bf16(af[i], bfr[j], acc[i][j], 0, 0, 0);
    __syncthreads();
  }
  #pragma unroll
  for (int i = 0; i < 4; i++) {
    #pragma unroll
    for (int j = 0; j < 4; j++) {
      #pragma unroll
      for (int r = 0; r < 4; r++) {
        int rr = row0 + wm + i * 16 + quad * 4 + r;
        int cc = col0 + wn + j * 16 + mrow;
        float v = acc[i][j][r];
        if (bias) v += bias[cc];
        C[(size_t)rr * N + cc] = v;
      }
    }
  }
}

// ---------------- causal depthwise conv(K=4) + SiLU (+ per-head l2norm) ----------------
// Writes [B,H,T,128] layout for the scan. post_mul folds the scan's q-scale
// into the l2norm multiplier (free: one extra mul on rs, not per element).
__global__ __launch_bounds__(256) void conv_silu_kernel(const float* __restrict__ Pre,
                                                        const float* __restrict__ cw,
                                                        float* __restrict__ outp,
                                                        int do_norm, float post_mul) {
  int bt = blockIdx.x;
  int b = bt >> 11, t = bt & (TT - 1);
  int tid = threadIdx.x;
  int ch0 = tid * 8;
  f32x4 wv[8];
  #pragma unroll
  for (int j = 0; j < 8; j++) wv[j] = *(const f32x4*)(cw + (size_t)(ch0 + j) * 4);
  float acc[8] = {0, 0, 0, 0, 0, 0, 0, 0};
  #pragma unroll
  for (int i = 0; i < 4; i++) {
    int tt = t - 3 + i;
    if (tt < 0) continue;
    const float* r = Pre + ((size_t)(b * TT + tt)) * HD + ch0;
    f32x4 a0 = *(const f32x4*)r;
    f32x4 a1 = *(const f32x4*)(r + 4);
    #pragma unroll
    for (int j = 0; j < 4; j++) {
      acc[j]     += a0[j] * wv[j][i];
      acc[4 + j] += a1[j] * wv[4 + j][i];
    }
  }
  float val[8];
  #pragma unroll
  for (int j = 0; j < 8; j++) val[j] = acc[j] / (1.f + expf(-acc[j]));   // SiLU
  if (do_norm) {
    float ss = 0.f;
    #pragma unroll
    for (int j = 0; j < 8; j++) ss += val[j] * val[j];
    ss = reduce16(ss);
    float rs = rsqrtf(ss + 1e-6f) * post_mul;
    #pragma unroll
    for (int j = 0; j < 8; j++) val[j] *= rs;
  }
  int h = tid >> 4, cc = (tid & 15) * 8;
  float* op = outp + (((size_t)(b * HH + h)) * TT + t) * 128 + cc;
  f32x4 o0, o1;
  #pragma unroll
  for (int j = 0; j < 4; j++) { o0[j] = val[j]; o1[j] = val[4 + j]; }
  *(f32x4*)op = o0;
  *(f32x4*)(op + 4) = o1;
}

// ---------------- beta = sigmoid(x @ Wb) -> [B,H,T] layout ----------------
__global__ __launch_bounds__(256) void beta_kernel(const float* __restrict__ x,
                                                   const float* __restrict__ Wb,
                                                   float* __restrict__ beta) {
  __shared__ float xs[2048];
  int bt = blockIdx.x, tid = threadIdx.x;
  int b = bt >> 11, t = bt & (TT - 1);
  const float* row = x + (size_t)bt * DD;
  #pragma unroll
  for (int i = 0; i < 2; i++)
    *(f32x4*)(xs + tid * 8 + i * 4) = *(const f32x4*)(row + tid * 8 + i * 4);
  __syncthreads();
  int h = tid >> 4, seg = tid & 15;
  float p = 0.f;
  for (int j = 0; j < 128; j++) {
    int d = seg * 128 + ((j + seg * 9) & 127);
    p += xs[d] * Wb[(size_t)d * HH + h];
  }
  p = reduce16(p);
  if (seg == 0) beta[((size_t)(b * HH + h)) * TT + t] = 1.f / (1.f + expf(-p));
}

// ---------------- gexp -> [B,H,T,128] layout ----------------
__global__ __launch_bounds__(256) void gexp_kernel(const float* __restrict__ g,
                                                   const float* __restrict__ A_log,
                                                   const float* __restrict__ dt_bias,
                                                   float* __restrict__ ge, int n) {
  int i = blockIdx.x * 256 + threadIdx.x;
  if (i >= n) return;
  int bt = i >> 11, ch = i & (HD - 1);
  int b = bt >> 11, t = bt & (TT - 1);
  int h = ch >> 7, c = ch & 127;
  float gv = g[i] + dt_bias[ch];
  float sp = (gv > 20.f) ? gv : log1pf(expf(gv));
  ge[(((size_t)(b * HH + h)) * TT + t) * 128 + c] = expf(-expf(A_log[h]) * sp);
}

// ---------------- KDA delta-rule scan: parallel-reduce restructure ----------------
// r7 post-mortem: sched pin neutral -> wall = serial work per step under
// in-order issue (2 serial DPP reduces/step, each with 2-wait-state hazards).
// Algebraic fix: with sd = g*S_{t-1},
//   p  = k.sd      (prediction)
//   oA = q.sd      (output, state part)
//   oB = q.k       (output, update part)
// are ALL independent of u -> one stage-interleaved reduce16x3 (runs at issue
// rate, sibling chains fill the DPP wait states). Then u = (v-p)*beta,
// S_t = sd + k*u, and o_t = q.S_t = oA + oB*u -- ONE FMA, no post-update
// reduce. Same sums reassociated (fp-safe at bf16 threshold).
// Parity-split reads (r4, conflict-free); per-chunk v*beta/beta reg preload;
// cndmask-keep store; q pre-scaled; bh=blk&31 XCD mapping (L2 dedup, r2).
// v and o alias: block only touches its own 16 columns; writes strictly behind reads.
__global__ __launch_bounds__(256, 1) void scan_kernel(const float* __restrict__ q,
                                                      const float* __restrict__ k,
                                                      const float* v,
                                                      const float* __restrict__ ge,
                                                      const float* __restrict__ beta,
                                                      float* o) {
  __shared__ __align__(16) float kbuf[2][SCH * 128];
  __shared__ __align__(16) float gbuf[2][SCH * 128];
  __shared__ __align__(16) float qbuf[2][SCH * 128];
  __shared__ __align__(16) float vbuf[2][SCH * 16];
  __shared__ __align__(16) float bbuf[TT];

  int blk = blockIdx.x;
  int bh = blk & 31;                        // same-bh blocks share an XCD
  int colblk = blk >> 5;                    // 0..7
  int tid = threadIdx.x;
  int w = tid >> 6, l = tid & 63;
  int grp = l >> 4, i = l & 15;
  int lcol = w * 4 + grp;                   // 0..15: column within block
  int col = colblk * 16 + lcol;             // 0..127: column within head

  // Parity-split 16B-unit offsets: groups 0,2 -> (even,odd); 1,3 -> (odd,even).
  int par = grp & 1;
  int of0 = (2 * i + par) * 4;              // float offset of lane's first 16B
  int of1 = (2 * i + (1 - par)) * 4;        // float offset of lane's second 16B

  const float* kbh = k    + (size_t)bh * TT * 128;
  const float* gbh = ge   + (size_t)bh * TT * 128;
  const float* qbh = q    + (size_t)bh * TT * 128;
  const float* vbh = v    + (size_t)bh * TT * 128;
  const float* bbh = beta + (size_t)bh * TT;
  float* obh = o + (size_t)bh * TT * 128;

  // stage whole beta sequence (8 KB) once
  #pragma unroll
  for (int j = 0; j < 2; j++) {
    int jj = w * 2 + j;
    async_ld16(bbh + jj * 256 + l * 4, (float*)bbuf + jj * 256);
  }
  // cooperative staging (wave role), contiguous source + linear LDS
  auto stage = [&](int cidx, int nb) {
    size_t t0 = (size_t)cidx * SCH;
    if (w == 0) {
      #pragma unroll
      for (int j = 0; j < 8; j++)
        async_ld16(kbh + t0 * 128 + j * 256 + l * 4, (float*)kbuf[nb] + j * 256);
    } else if (w == 1) {
      #pragma unroll
      for (int j = 0; j < 8; j++)
        async_ld16(gbh + t0 * 128 + j * 256 + l * 4, (float*)gbuf[nb] + j * 256);
    } else if (w == 2) {
      #pragma unroll
      for (int j = 0; j < 8; j++)
        async_ld16(qbh + t0 * 128 + j * 256 + l * 4, (float*)qbuf[nb] + j * 256);
    } else {
      async_ld16(vbh + (t0 + (size_t)(l >> 2)) * 128 + colblk * 16 + (l & 3) * 4,
                 (float*)vbuf[nb]);
    }
  };
  stage(0, 0);
  __syncthreads();

  f32x4 s0 = {0.f, 0.f, 0.f, 0.f}, s1 = {0.f, 0.f, 0.f, 0.f};
  float okeep = 0.f;

  for (int c = 0; c < TT / SCH; c++) {
    int cb = c & 1, nb = cb ^ 1;
    // async-stage next chunk; latency hidden behind 16 compute steps
    if (c + 1 < TT / SCH) stage(c + 1, nb);

    const float* kc = (const float*)kbuf[cb];
    const float* gc = (const float*)gbuf[cb];
    const float* qc = (const float*)qbuf[cb];
    // per-chunk preload: v*beta and beta into registers (waits off step loop)
    float vbt[SCH], btp[SCH];
    #pragma unroll
    for (int s = 0; s < SCH; s++) {
      float vv = ((const float*)vbuf[cb])[s * 16 + lcol];  // 16-lane broadcast
      float bb = bbuf[c * SCH + s];                        // uniform
      btp[s] = bb;
      vbt[s] = vv * bb;
    }
    // register-rotate: load step s+1 while computing step s
    f32x4 k0 = *(const f32x4*)(kc + of0), k1 = *(const f32x4*)(kc + of1);
    f32x4 g0 = *(const f32x4*)(gc + of0), g1 = *(const f32x4*)(gc + of1);
    f32x4 q0 = *(const f32x4*)(qc + of0), q1 = *(const f32x4*)(qc + of1);
    #pragma unroll
    for (int s = 0; s < SCH; s++) {
      f32x4 k0n, k1n, g0n, g1n, q0n, q1n;
      if (s + 1 < SCH) {
        const float* kp = kc + (s + 1) * 128;
        const float* gp = gc + (s + 1) * 128;
        const float* qp = qc + (s + 1) * 128;
        k0n = *(const f32x4*)(kp + of0); k1n = *(const f32x4*)(kp + of1);
        g0n = *(const f32x4*)(gp + of0); g1n = *(const f32x4*)(gp + of1);
        q0n = *(const f32x4*)(qp + of0); q1n = *(const f32x4*)(qp + of1);
      }
      // decayed state once; p, oA, oB all independent of u
      f32x4 sd0 = s0 * g0, sd1 = s1 * g1;
      f32x4 pp = k0 * sd0 + k1 * sd1;
      f32x4 oa = q0 * sd0 + q1 * sd1;
      f32x4 ob = q0 * k0 + q1 * k1;
      float p  = (pp[0] + pp[1]) + (pp[2] + pp[3]);
      float A  = (oa[0] + oa[1]) + (oa[2] + oa[3]);
      float Bv = (ob[0] + ob[1]) + (ob[2] + ob[3]);
      reduce16x3(p, A, Bv);                  // interleaved, issue-rate
      float u = fmaf(-btp[s], p, vbt[s]);    // u = (v - p)*beta
      s0 = sd0 + k0 * u; s1 = sd1 + k1 * u;  // S_t = sd + k*u
      float po = fmaf(Bv, u, A);             // o = q.S_t = oA + oB*u
      okeep = (i == s) ? po : okeep;         // cndmask, no divergence
      if (s + 1 < SCH) {
        k0 = k0n; k1 = k1n; g0 = g0n; g1 = g1n; q0 = q0n; q1 = q1n;
      }
    }
    // one store per chunk: lane i holds step i's output for its column
    obh[((size_t)c * SCH + i) * 128 + col] = okeep;
    __syncthreads();
  }
}

// ---------------- gated RMSNorm -> bf16 (o in [B,H,T,128]) ----------------
__global__ __launch_bounds__(256) void out_norm_kernel(const float* o,
                                                       const float* __restrict__ gate,
                                                       const float* __restrict__ w,
                                                       unsigned short* __restrict__ onb) {
  int bt = blockIdx.x, tid = threadIdx.x;
  int b = bt >> 11, t = bt & (TT - 1);
  int h = tid >> 4, seg = tid & 15;
  size_t obase = (((size_t)(b * HH + h)) * TT + t) * 128 + seg * 8;
  size_t gbase = (size_t)bt * HD + (size_t)h * 128 + seg * 8;
  f32x4 o0 = *(const f32x4*)(o + obase);
  f32x4 o1 = *(const f32x4*)(o + obase + 4);
  float ss = 0.f;
  #pragma unroll
  for (int j = 0; j < 4; j++) ss += o0[j] * o0[j] + o1[j] * o1[j];
  ss = reduce16(ss);
  float rs = rsqrtf(ss * (1.f / 128.f) + 1e-5f);
  u16x4 r0, r1;
  #pragma unroll
  for (int j = 0; j < 4; j++) {
    float gv0 = gate[gbase + j];
    float gv1 = gate[gbase + 4 + j];
    float a0 = o0[j] * rs * w[seg * 8 + j] * (gv0 / (1.f + expf(-gv0)));
    float a1 = o1[j] * rs * w[seg * 8 + 4 + j] * (gv1 / (1.f + expf(-gv1)));
    r0[j] = f2b(a0);
    r1[j] = f2b(a1);
  }
  *(u16x4*)(onb + gbase) = r0;
  *(u16x4*)(onb + gbase + 4) = r1;
}

// ---------------- driver ----------------
extern "C" void kernel_launch(void* const* d_in, const int* in_sizes, int n_in,
                              void* d_out, int out_size, void* d_ws, size_t ws_size,
                              hipStream_t stream) {
  const float* x       = (const float*)d_in[0];
  const float* Wq      = (const float*)d_in[1];
  const float* Wk      = (const float*)d_in[2];
  const float* Wv      = (const float*)d_in[3];
  const float* cq      = (const float*)d_in[4];
  const float* ck      = (const float*)d_in[5];
  const float* cv      = (const float*)d_in[6];
  const float* Wf1     = (const float*)d_in[7];
  const float* Wf2     = (const float*)d_in[8];
  const float* Wb      = (const float*)d_in[9];
  const float* A_log   = (const float*)d_in[10];
  const float* dt_bias = (const float*)d_in[11];
  const float* Wg      = (const float*)d_in[12];
  const float* bg      = (const float*)d_in[13];
  const float* onw     = (const float*)d_in[14];
  const float* Wo      = (const float*)d_in[15];
  float* out = (float*)d_out;

  char* ws = (char*)d_ws;
  unsigned short* WT  = (unsigned short*)(ws);                       //  8 MB rotating W^T
  unsigned short* xb  = (unsigned short*)(ws + ((size_t)8  << 20));  // 16 MB bf16 x
  float* P    = (float*)(ws + ((size_t)24  << 20));                  // 32 MB rotating pre/gate
  float* qb   = (float*)(ws + ((size_t)56  << 20));                  // 32 MB [B,H,T,128]
  float* kb   = (float*)(ws + ((size_t)88  << 20));                  // 32 MB [B,H,T,128]
  float* vb   = (float*)(ws + ((size_t)120 << 20));                  // 32 MB (aliased by o)
  float* geb  = (float*)(ws + ((size_t)152 << 20));                  // 32 MB [B,H,T,128]
  float* betab= (float*)(ws + ((size_t)184 << 20));                  // 256 KB [B,H,T]
  float* f1   = (float*)(ws + ((size_t)185 << 20));                  //   2 MB
  unsigned short* f1b = (unsigned short*)(ws + ((size_t)187 << 20)); //   1 MB
  unsigned short* onb = xb;   // xb dead after gate GEMM
  float* gateb = P;           // P reused as gate buffer
  float* ob    = vb;          // scan output aliases v

  dim3 tb(32, 8);
  dim3 gemm_grid(HD / 128, MM / 128);

  cast_f32_bf16<<<(MM * DD / 4 + 255) / 256, 256, 0, stream>>>(x, xb, MM * DD / 4);

  // q path (scan scale 128^-0.5 folded into l2norm)
  transpose_cast<<<dim3(HD / 32, DD / 32), tb, 0, stream>>>(Wq, WT, DD, HD);
  gemm_bf16<<<gemm_grid, 256, 0, stream>>>(xb, WT, P, nullptr, MM, HD, DD);
  conv_silu_kernel<<<MM, 256, 0, stream>>>(P, cq, qb, 1, 0.08838834764831845f);
  // k path
  transpose_cast<<<dim3(HD / 32, DD / 32), tb, 0, stream>>>(Wk, WT, DD, HD);
  gemm_bf16<<<gemm_grid, 256, 0, stream>>>(xb, WT, P, nullptr, MM, HD, DD);
  conv_silu_kernel<<<MM, 256, 0, stream>>>(P, ck, kb, 1, 1.0f);
  // v path
  transpose_cast<<<dim3(HD / 32, DD / 32), tb, 0, stream>>>(Wv, WT, DD, HD);
  gemm_bf16<<<gemm_grid, 256, 0, stream>>>(xb, WT, P, nullptr, MM, HD, DD);
  conv_silu_kernel<<<MM, 256, 0, stream>>>(P, cv, vb, 0, 1.0f);

  // beta
  beta_kernel<<<MM, 256, 0, stream>>>(x, Wb, betab);

  // g chain
  transpose_cast<<<dim3(128 / 32, DD / 32), tb, 0, stream>>>(Wf1, WT, DD, 128);
  gemm_bf16<<<dim3(1, MM / 128), 256, 0, stream>>>(xb, WT, f1, nullptr, MM, 128, DD);
  cast_f32_bf16<<<(MM * 128 / 4 + 255) / 256, 256, 0, stream>>>(f1, f1b, MM * 128 / 4);
  transpose_cast<<<dim3(HD / 32, 128 / 32), tb, 0, stream>>>(Wf2, WT, 128, HD);
  gemm_bf16<<<gemm_grid, 256, 0, stream>>>(f1b, WT, P, nullptr, MM, HD, 128);
  gexp_kernel<<<(MM * HD + 255) / 256, 256, 0, stream>>>(P, A_log, dt_bias, geb, MM * HD);

  // gate = x@Wg + bg
  transpose_cast<<<dim3(HD / 32, DD / 32), tb, 0, stream>>>(Wg, WT, DD, HD);
  gemm_bf16<<<gemm_grid, 256, 0, stream>>>(xb, WT, gateb, bg, MM, HD, DD);

  // chunked-pipeline delta-rule scan (parallel triple-reduce restructure)
  scan_kernel<<<BB * HH * 8, 256, 0, stream>>>(qb, kb, vb, geb, betab, ob);

  // gated RMSNorm -> bf16
  out_norm_kernel<<<MM, 256, 0, stream>>>(ob, gateb, onw, onb);

  // final projection
  transpose_cast<<<dim3(DD / 32, HD / 32), tb, 0, stream>>>(Wo, WT, HD, DD);
  gemm_bf16<<<dim3(DD / 128, MM / 128), 256, 0, stream>>>(onb, WT, out, nullptr, MM, DD, HD);
}

// Round 9
// 1152.010 us; speedup vs baseline: 1.0297x; 1.0297x over previous
//
#include <hip/hip_runtime.h>
#include <stdint.h>

// Problem constants
#define BB 2
#define TT 2048
#define DD 2048
#define HH 16
#define HD 2048     // H*Dk = H*Dv
#define MM 4096     // B*T
#define SCH 16      // scan chunk steps

typedef float f32x4 __attribute__((ext_vector_type(4)));
typedef __bf16 bf16x8 __attribute__((ext_vector_type(8)));
typedef unsigned short u16x4 __attribute__((ext_vector_type(4)));
typedef unsigned int u32x4 __attribute__((ext_vector_type(4)));

__device__ __forceinline__ unsigned short f2b(float f) {
  unsigned int u = __float_as_uint(f);
  u += 0x7FFFu + ((u >> 16) & 1u);   // RNE
  return (unsigned short)(u >> 16);
}

__device__ __forceinline__ void async_ld16(const void* g, void* l) {
  typedef __attribute__((address_space(3))) void as3_t;
  typedef const __attribute__((address_space(1))) void as1_t;
  // NOTE: LDS arg must be WAVE-UNIFORM base; HW adds lane*16 itself.
  __builtin_amdgcn_global_load_lds((as1_t*)(uintptr_t)g,
                                   (as3_t*)(unsigned int)(uintptr_t)l, 16, 0, 0);
}

// ---- DPP 16-lane all-reduce (VALU-pipe). r6 lesson: BUILTIN form only ----
template <int CTRL>
__device__ __forceinline__ float dpp_add(float x) {
  int y = __builtin_amdgcn_update_dpp(0, __float_as_int(x), CTRL, 0xF, 0xF, false);
  return x + __int_as_float(y);
}
__device__ __forceinline__ float reduce16(float x) {
  x = dpp_add<0xB1>(x);    // quad_perm [1,0,3,2]
  x = dpp_add<0x4E>(x);    // quad_perm [2,3,0,1]
  x = dpp_add<0x124>(x);   // row_ror:4
  x = dpp_add<0x128>(x);   // row_ror:8
  return x;
}

// ---------------- cast f32 -> bf16 (vectorized x4) ----------------
__global__ __launch_bounds__(256) void cast_f32_bf16(const float* __restrict__ in,
                                                     unsigned short* __restrict__ out,
                                                     int n4) {
  int i = blockIdx.x * 256 + threadIdx.x;
  if (i >= n4) return;
  f32x4 v = *(const f32x4*)(in + (size_t)i * 4);
  u16x4 r;
  #pragma unroll
  for (int j = 0; j < 4; j++) r[j] = f2b(v[j]);
  *(u16x4*)(out + (size_t)i * 4) = r;
}

// ---------------- transpose + cast: in f32 [R,C] -> out bf16 [C,R] ----------------
__global__ __launch_bounds__(256) void transpose_cast(const float* __restrict__ in,
                                                      unsigned short* __restrict__ out,
                                                      int R, int C) {
  __shared__ float tile[32][33];
  int bx = blockIdx.x * 32, by = blockIdx.y * 32;
  int tx = threadIdx.x, ty = threadIdx.y;
  #pragma unroll
  for (int i = 0; i < 32; i += 8)
    tile[ty + i][tx] = in[(size_t)(by + ty + i) * C + bx + tx];
  __syncthreads();
  #pragma unroll
  for (int i = 0; i < 32; i += 8)
    out[(size_t)(bx + ty + i) * R + by + tx] = f2b(tile[tx][ty + i]);
}

// ---------------- shared GEMM core macro-free: 128x128 tile, bf16 MFMA ----------------
// (3 epilogue variants below share this loop structure verbatim.)
#define GEMM_PROLOGUE_AND_LOOP                                                         \
  __shared__ __align__(16) unsigned short As[128 * 32];                                \
  __shared__ __align__(16) unsigned short Bs[128 * 32];                                \
  int tid = threadIdx.x;                                                               \
  int l = tid & 63, w = tid >> 6;                                                      \
  int nbx = gridDim.x;                                                                 \
  int tot = nbx * gridDim.y;                                                           \
  int id = blockIdx.y * nbx + blockIdx.x;                                              \
  int nid = id;                                                                        \
  if ((tot & 7) == 0) { int per = tot >> 3; nid = (id & 7) * per + (id >> 3); }        \
  int row0 = (nid / nbx) * 128, col0 = (nid % nbx) * 128;                              \
  int wm = (w >> 1) * 64, wn = (w & 1) * 64;                                           \
  const f32x4 fz = {0.f, 0.f, 0.f, 0.f};                                               \
  f32x4 acc[4][4];                                                                     \
  _Pragma("unroll") for (int i = 0; i < 4; i++)                                        \
    _Pragma("unroll") for (int j = 0; j < 4; j++) acc[i][j] = fz;                      \
  int srow = l >> 2, skoff = (l & 3) * 8;                                              \
  int quad = l >> 4, mrow = l & 15;                                                    \
  for (int kt = 0; kt < K; kt += 32) {                                                 \
    _Pragma("unroll") for (int i = 0; i < 2; i++) {                                    \
      int c = w * 2 + i;                                                               \
      const unsigned short* gA = A + (size_t)(row0 + c * 16 + srow) * K + kt + skoff;  \
      const unsigned short* gB = Bt + (size_t)(col0 + c * 16 + srow) * K + kt + skoff; \
      async_ld16(gA, As + c * 512);                                                    \
      async_ld16(gB, Bs + c * 512);                                                    \
    }                                                                                  \
    __syncthreads();                                                                   \
    bf16x8 af[4], bfr[4];                                                              \
    _Pragma("unroll") for (int i = 0; i < 4; i++)                                      \
      af[i] = *(const bf16x8*)(As + (wm + i * 16 + mrow) * 32 + quad * 8);             \
    _Pragma("unroll") for (int j = 0; j < 4; j++)                                      \
      bfr[j] = *(const bf16x8*)(Bs + (wn + j * 16 + mrow) * 32 + quad * 8);            \
    _Pragma("unroll") for (int i = 0; i < 4; i++)                                      \
      _Pragma("unroll") for (int j = 0; j < 4; j++)                                    \
        acc[i][j] = __builtin_amdgcn_mfma_f32_16x16x32_bf16(af[i], bfr[j], acc[i][j],  \
                                                            0, 0, 0);                  \
    __syncthreads();                                                                   \
  }

// ---- variant 1: f32 output, optional bias (row layout) ----
__global__ __launch_bounds__(256) void gemm_bf16(const unsigned short* __restrict__ A,
                                                 const unsigned short* __restrict__ Bt,
                                                 float* __restrict__ C,
                                                 const float* __restrict__ bias,
                                                 int M, int N, int K) {
  GEMM_PROLOGUE_AND_LOOP
  #pragma unroll
  for (int i = 0; i < 4; i++)
    #pragma unroll
    for (int j = 0; j < 4; j++)
      #pragma unroll
      for (int r = 0; r < 4; r++) {
        int rr = row0 + wm + i * 16 + quad * 4 + r;
        int cc = col0 + wn + j * 16 + mrow;
        float v = acc[i][j][r];
        if (bias) v += bias[cc];
        C[(size_t)rr * N + cc] = v;
      }
}

// ---- variant 2: bf16 output + bias (row layout) — used for the gate ----
__global__ __launch_bounds__(256) void gemm_bf16_bout(const unsigned short* __restrict__ A,
                                                      const unsigned short* __restrict__ Bt,
                                                      unsigned short* __restrict__ C,
                                                      const float* __restrict__ bias,
                                                      int M, int N, int K) {
  GEMM_PROLOGUE_AND_LOOP
  #pragma unroll
  for (int i = 0; i < 4; i++)
    #pragma unroll
    for (int j = 0; j < 4; j++)
      #pragma unroll
      for (int r = 0; r < 4; r++) {
        int rr = row0 + wm + i * 16 + quad * 4 + r;
        int cc = col0 + wn + j * 16 + mrow;
        C[(size_t)rr * N + cc] = f2b(acc[i][j][r] + bias[cc]);
      }
}

// ---- variant 3: fused q|k|v (N=6144), bf16 output routed into SCAN LAYOUT ----
// cc>>11 selects the sub-tensor; within a 128-col tile, sub and h are uniform.
// dst index = ((b*HH + h)*TT + t)*128 + c  with b=rr>>11, t=rr&2047.
__global__ __launch_bounds__(256) void gemm_qkv(const unsigned short* __restrict__ A,
                                                const unsigned short* __restrict__ Bt,
                                                unsigned short* __restrict__ Dq,
                                                unsigned short* __restrict__ Dk,
                                                unsigned short* __restrict__ Dv,
                                                int M, int N, int K) {
  GEMM_PROLOGUE_AND_LOOP
  {
    int cc0 = col0 + wn + mrow;          // sub/h uniform across i,j? h varies with j*16
    (void)cc0;
  }
  #pragma unroll
  for (int i = 0; i < 4; i++)
    #pragma unroll
    for (int j = 0; j < 4; j++)
      #pragma unroll
      for (int r = 0; r < 4; r++) {
        int rr = row0 + wm + i * 16 + quad * 4 + r;
        int cc = col0 + wn + j * 16 + mrow;
        int sub = cc >> 11;
        int ch = cc & (HD - 1);
        int h = ch >> 7, c2 = ch & 127;
        int b = rr >> 11, t = rr & (TT - 1);
        unsigned short* dst = (sub == 0) ? Dq : (sub == 1) ? Dk : Dv;
        dst[(((size_t)(b * HH + h)) * TT + t) * 128 + c2] = f2b(acc[i][j][r]);
      }
}

// ---------------- causal depthwise conv(K=4) + SiLU (+ per-head l2norm) ----------------
// Input: bf16 SCAN layout [B,H,T,128] (written by gemm_qkv). Output: f32 scan
// layout. post_mul folds the scan's q-scale into the l2norm multiplier.
__global__ __launch_bounds__(256) void conv_silu_kernel(const unsigned short* __restrict__ Pre,
                                                        const float* __restrict__ cw,
                                                        float* __restrict__ outp,
                                                        int do_norm, float post_mul) {
  int bt = blockIdx.x;
  int b = bt >> 11, t = bt & (TT - 1);
  int tid = threadIdx.x;
  int ch0 = tid * 8;
  int h = tid >> 4, c0 = (tid & 15) * 8;
  f32x4 wv[8];
  #pragma unroll
  for (int j = 0; j < 8; j++) wv[j] = *(const f32x4*)(cw + (size_t)(ch0 + j) * 4);
  float acc[8] = {0, 0, 0, 0, 0, 0, 0, 0};
  const unsigned short* base = Pre + (((size_t)(b * HH + h)) * TT) * 128 + c0;
  #pragma unroll
  for (int i = 0; i < 4; i++) {
    int tt = t - 3 + i;
    if (tt < 0) continue;
    u32x4 raw = *(const u32x4*)(base + (size_t)tt * 128);
    float e[8];
    #pragma unroll
    for (int jj = 0; jj < 4; jj++) {
      e[2 * jj]     = __uint_as_float(raw[jj] << 16);
      e[2 * jj + 1] = __uint_as_float(raw[jj] & 0xffff0000u);
    }
    #pragma unroll
    for (int j = 0; j < 8; j++) acc[j] += e[j] * wv[j][i];
  }
  float val[8];
  #pragma unroll
  for (int j = 0; j < 8; j++) val[j] = acc[j] / (1.f + expf(-acc[j]));   // SiLU
  if (do_norm) {
    float ss = 0.f;
    #pragma unroll
    for (int j = 0; j < 8; j++) ss += val[j] * val[j];
    ss = reduce16(ss);
    float rs = rsqrtf(ss + 1e-6f) * post_mul;
    #pragma unroll
    for (int j = 0; j < 8; j++) val[j] *= rs;
  }
  float* op = outp + (((size_t)(b * HH + h)) * TT + t) * 128 + c0;
  f32x4 o0, o1;
  #pragma unroll
  for (int j = 0; j < 4; j++) { o0[j] = val[j]; o1[j] = val[4 + j]; }
  *(f32x4*)op = o0;
  *(f32x4*)(op + 4) = o1;
}

// ---------------- beta = sigmoid(x @ Wb) -> [B,H,T] layout ----------------
__global__ __launch_bounds__(256) void beta_kernel(const float* __restrict__ x,
                                                   const float* __restrict__ Wb,
                                                   float* __restrict__ beta) {
  __shared__ float xs[2048];
  int bt = blockIdx.x, tid = threadIdx.x;
  int b = bt >> 11, t = bt & (TT - 1);
  const float* row = x + (size_t)bt * DD;
  #pragma unroll
  for (int i = 0; i < 2; i++)
    *(f32x4*)(xs + tid * 8 + i * 4) = *(const f32x4*)(row + tid * 8 + i * 4);
  __syncthreads();
  int h = tid >> 4, seg = tid & 15;
  float p = 0.f;
  for (int j = 0; j < 128; j++) {
    int d = seg * 128 + ((j + seg * 9) & 127);
    p += xs[d] * Wb[(size_t)d * HH + h];
  }
  p = reduce16(p);
  if (seg == 0) beta[((size_t)(b * HH + h)) * TT + t] = 1.f / (1.f + expf(-p));
}

// ---------------- gexp -> [B,H,T,128] layout ----------------
__global__ __launch_bounds__(256) void gexp_kernel(const float* __restrict__ g,
                                                   const float* __restrict__ A_log,
                                                   const float* __restrict__ dt_bias,
                                                   float* __restrict__ ge, int n) {
  int i = blockIdx.x * 256 + threadIdx.x;
  if (i >= n) return;
  int bt = i >> 11, ch = i & (HD - 1);
  int b = bt >> 11, t = bt & (TT - 1);
  int h = ch >> 7, c = ch & 127;
  float gv = g[i] + dt_bias[ch];
  float sp = (gv > 20.f) ? gv : log1pf(expf(gv));
  ge[(((size_t)(b * HH + h)) * TT + t) * 128 + c] = expf(-expf(A_log[h]) * sp);
}

// ---------------- KDA delta-rule scan (r7 form — measured fastest, 354µs) ----------------
// Structural floor at 1 wave/SIMD: ~24 ds_read_b128/step/CU (LDS-pipe ~290cyc)
// + unhidden chain. Parity-split reads (conflict-free); per-chunk v*beta/beta
// reg preload; cndmask-keep store; q pre-scaled; kg=k*g off the critical path;
// bh=blk&31 XCD mapping (L2 dedup). v and o alias.
__global__ __launch_bounds__(256, 1) void scan_kernel(const float* __restrict__ q,
                                                      const float* __restrict__ k,
                                                      const float* v,
                                                      const float* __restrict__ ge,
                                                      const float* __restrict__ beta,
                                                      float* o) {
  __shared__ __align__(16) float kbuf[2][SCH * 128];
  __shared__ __align__(16) float gbuf[2][SCH * 128];
  __shared__ __align__(16) float qbuf[2][SCH * 128];
  __shared__ __align__(16) float vbuf[2][SCH * 16];
  __shared__ __align__(16) float bbuf[TT];

  int blk = blockIdx.x;
  int bh = blk & 31;
  int colblk = blk >> 5;
  int tid = threadIdx.x;
  int w = tid >> 6, l = tid & 63;
  int grp = l >> 4, i = l & 15;
  int lcol = w * 4 + grp;
  int col = colblk * 16 + lcol;

  int par = grp & 1;
  int of0 = (2 * i + par) * 4;
  int of1 = (2 * i + (1 - par)) * 4;

  const float* kbh = k    + (size_t)bh * TT * 128;
  const float* gbh = ge   + (size_t)bh * TT * 128;
  const float* qbh = q    + (size_t)bh * TT * 128;
  const float* vbh = v    + (size_t)bh * TT * 128;
  const float* bbh = beta + (size_t)bh * TT;
  float* obh = o + (size_t)bh * TT * 128;

  #pragma unroll
  for (int j = 0; j < 2; j++) {
    int jj = w * 2 + j;
    async_ld16(bbh + jj * 256 + l * 4, (float*)bbuf + jj * 256);
  }
  auto stage = [&](int cidx, int nb) {
    size_t t0 = (size_t)cidx * SCH;
    if (w == 0) {
      #pragma unroll
      for (int j = 0; j < 8; j++)
        async_ld16(kbh + t0 * 128 + j * 256 + l * 4, (float*)kbuf[nb] + j * 256);
    } else if (w == 1) {
      #pragma unroll
      for (int j = 0; j < 8; j++)
        async_ld16(gbh + t0 * 128 + j * 256 + l * 4, (float*)gbuf[nb] + j * 256);
    } else if (w == 2) {
      #pragma unroll
      for (int j = 0; j < 8; j++)
        async_ld16(qbh + t0 * 128 + j * 256 + l * 4, (float*)qbuf[nb] + j * 256);
    } else {
      async_ld16(vbh + (t0 + (size_t)(l >> 2)) * 128 + colblk * 16 + (l & 3) * 4,
                 (float*)vbuf[nb]);
    }
  };
  stage(0, 0);
  __syncthreads();

  f32x4 s0 = {0.f, 0.f, 0.f, 0.f}, s1 = {0.f, 0.f, 0.f, 0.f};
  float okeep = 0.f;

  for (int c = 0; c < TT / SCH; c++) {
    int cb = c & 1, nb = cb ^ 1;
    if (c + 1 < TT / SCH) stage(c + 1, nb);

    const float* kc = (const float*)kbuf[cb];
    const float* gc = (const float*)gbuf[cb];
    const float* qc = (const float*)qbuf[cb];
    float vbt[SCH], btp[SCH];
    #pragma unroll
    for (int s = 0; s < SCH; s++) {
      float vv = ((const float*)vbuf[cb])[s * 16 + lcol];
      float bb = bbuf[c * SCH + s];
      btp[s] = bb;
      vbt[s] = vv * bb;
    }
    f32x4 k0 = *(const f32x4*)(kc + of0), k1 = *(const f32x4*)(kc + of1);
    f32x4 g0 = *(const f32x4*)(gc + of0), g1 = *(const f32x4*)(gc + of1);
    f32x4 q0 = *(const f32x4*)(qc + of0), q1 = *(const f32x4*)(qc + of1);
    #pragma unroll
    for (int s = 0; s < SCH; s++) {
      f32x4 k0n, k1n, g0n, g1n, q0n, q1n;
      if (s + 1 < SCH) {
        const float* kp = kc + (s + 1) * 128;
        const float* gp = gc + (s + 1) * 128;
        const float* qp = qc + (s + 1) * 128;
        k0n = *(const f32x4*)(kp + of0); k1n = *(const f32x4*)(kp + of1);
        g0n = *(const f32x4*)(gp + of0); g1n = *(const f32x4*)(gp + of1);
        q0n = *(const f32x4*)(qp + of0); q1n = *(const f32x4*)(qp + of1);
      }
      f32x4 kg0 = k0 * g0, kg1 = k1 * g1;
      f32x4 pp = kg0 * s0 + kg1 * s1;
      float p = (pp[0] + pp[1]) + (pp[2] + pp[3]);
      p = reduce16(p);
      s0 *= g0; s1 *= g1;
      float u = fmaf(-btp[s], p, vbt[s]);
      s0 += k0 * u; s1 += k1 * u;
      f32x4 oo = q0 * s0 + q1 * s1;
      float po = (oo[0] + oo[1]) + (oo[2] + oo[3]);
      po = reduce16(po);
      okeep = (i == s) ? po : okeep;
      if (s + 1 < SCH) {
        k0 = k0n; k1 = k1n; g0 = g0n; g1 = g1n; q0 = q0n; q1 = q1n;
      }
    }
    obh[((size_t)c * SCH + i) * 128 + col] = okeep;
    __syncthreads();
  }
}

// ---------------- gated RMSNorm -> bf16 (o f32 scan layout; gate bf16 row layout) ----------------
__global__ __launch_bounds__(256) void out_norm_kernel(const float* o,
                                                       const unsigned short* __restrict__ gate,
                                                       const float* __restrict__ w,
                                                       unsigned short* __restrict__ onb) {
  int bt = blockIdx.x, tid = threadIdx.x;
  int b = bt >> 11, t = bt & (TT - 1);
  int h = tid >> 4, seg = tid & 15;
  size_t obase = (((size_t)(b * HH + h)) * TT + t) * 128 + seg * 8;
  size_t gbase = (size_t)bt * HD + (size_t)h * 128 + seg * 8;
  f32x4 o0 = *(const f32x4*)(o + obase);
  f32x4 o1 = *(const f32x4*)(o + obase + 4);
  u32x4 graw = *(const u32x4*)(gate + gbase);
  float gv[8];
  #pragma unroll
  for (int jj = 0; jj < 4; jj++) {
    gv[2 * jj]     = __uint_as_float(graw[jj] << 16);
    gv[2 * jj + 1] = __uint_as_float(graw[jj] & 0xffff0000u);
  }
  float ss = 0.f;
  #pragma unroll
  for (int j = 0; j < 4; j++) ss += o0[j] * o0[j] + o1[j] * o1[j];
  ss = reduce16(ss);
  float rs = rsqrtf(ss * (1.f / 128.f) + 1e-5f);
  u16x4 r0, r1;
  #pragma unroll
  for (int j = 0; j < 4; j++) {
    float gv0 = gv[j];
    float gv1 = gv[4 + j];
    float a0 = o0[j] * rs * w[seg * 8 + j] * (gv0 / (1.f + expf(-gv0)));
    float a1 = o1[j] * rs * w[seg * 8 + 4 + j] * (gv1 / (1.f + expf(-gv1)));
    r0[j] = f2b(a0);
    r1[j] = f2b(a1);
  }
  *(u16x4*)(onb + gbase) = r0;
  *(u16x4*)(onb + gbase + 4) = r1;
}

// ---------------- driver ----------------
// Workspace layout (byte offsets, high-water 188 MB == previous session's):
//   [0,24)    WT      bf16 W^T (24MB for fused qkv; later reused by Wg/Wo/Wf*)
//   [24,40)   xb      bf16 x (dies after qkv+f1 gemms; reused as onb)
//   [40,72)   geb     f32 scan-layout decay
//   [72,104)  P2      f32 Wf2-gemm out (dies at gexp) -> then B1,B2 -> then vc/ob
//   [72,88)   B1      bf16 q-pre (scan layout)       [over P2, after gexp]
//   [88,104)  B2      bf16 k-pre
//   [104,120) B3      bf16 v-pre -> then gateb (bf16 row layout)
//   [120,152) qc      f32 scan layout
//   [152,184) kc      f32 scan layout
//   [72,104)  vc/ob   f32 scan layout [over B1,B2 after convs q,k]
//   [184,186) f1 | [186,187) f1b | [187,187.25) betab
extern "C" void kernel_launch(void* const* d_in, const int* in_sizes, int n_in,
                              void* d_out, int out_size, void* d_ws, size_t ws_size,
                              hipStream_t stream) {
  const float* x       = (const float*)d_in[0];
  const float* Wq      = (const float*)d_in[1];
  const float* Wk      = (const float*)d_in[2];
  const float* Wv      = (const float*)d_in[3];
  const float* cq      = (const float*)d_in[4];
  const float* ck      = (const float*)d_in[5];
  const float* cv      = (const float*)d_in[6];
  const float* Wf1     = (const float*)d_in[7];
  const float* Wf2     = (const float*)d_in[8];
  const float* Wb      = (const float*)d_in[9];
  const float* A_log   = (const float*)d_in[10];
  const float* dt_bias = (const float*)d_in[11];
  const float* Wg      = (const float*)d_in[12];
  const float* bg      = (const float*)d_in[13];
  const float* onw     = (const float*)d_in[14];
  const float* Wo      = (const float*)d_in[15];
  float* out = (float*)d_out;

  char* ws = (char*)d_ws;
  unsigned short* WT  = (unsigned short*)(ws);
  unsigned short* xb  = (unsigned short*)(ws + ((size_t)24 << 20));
  float* geb          = (float*)(ws + ((size_t)40 << 20));
  float* P2           = (float*)(ws + ((size_t)72 << 20));
  unsigned short* B1  = (unsigned short*)(ws + ((size_t)72 << 20));
  unsigned short* B2  = (unsigned short*)(ws + ((size_t)88 << 20));
  unsigned short* B3  = (unsigned short*)(ws + ((size_t)104 << 20));
  float* qc           = (float*)(ws + ((size_t)120 << 20));
  float* kc           = (float*)(ws + ((size_t)152 << 20));
  float* vc           = (float*)(ws + ((size_t)72 << 20));
  unsigned short* gateb = (unsigned short*)(ws + ((size_t)104 << 20));
  float* f1           = (float*)(ws + ((size_t)184 << 20));
  unsigned short* f1b = (unsigned short*)(ws + ((size_t)186 << 20));
  float* betab        = (float*)(ws + ((size_t)187 << 20));
  unsigned short* onb = xb;
  float* ob = vc;

  dim3 tb(32, 8);

  // 1. x -> bf16
  cast_f32_bf16<<<(MM * DD / 4 + 255) / 256, 256, 0, stream>>>(x, xb, MM * DD / 4);

  // 2-5. g chain FIRST (P2 region is reused by B1/B2 afterwards)
  transpose_cast<<<dim3(128 / 32, DD / 32), tb, 0, stream>>>(Wf1, WT, DD, 128);
  gemm_bf16<<<dim3(1, MM / 128), 256, 0, stream>>>(xb, WT, f1, nullptr, MM, 128, DD);
  cast_f32_bf16<<<(MM * 128 / 4 + 255) / 256, 256, 0, stream>>>(f1, f1b, MM * 128 / 4);
  transpose_cast<<<dim3(HD / 32, 128 / 32), tb, 0, stream>>>(Wf2, WT, 128, HD);
  gemm_bf16<<<dim3(HD / 128, MM / 128), 256, 0, stream>>>(f1b, WT, P2, nullptr, MM, HD, 128);
  gexp_kernel<<<(MM * HD + 255) / 256, 256, 0, stream>>>(P2, A_log, dt_bias, geb, MM * HD);

  // 6. beta
  beta_kernel<<<MM, 256, 0, stream>>>(x, Wb, betab);

  // 7. fused q|k|v weights -> WT rows [0,2048) [2048,4096) [4096,6144)
  transpose_cast<<<dim3(HD / 32, DD / 32), tb, 0, stream>>>(Wq, WT, DD, HD);
  transpose_cast<<<dim3(HD / 32, DD / 32), tb, 0, stream>>>(Wk, WT + (size_t)2048 * 2048, DD, HD);
  transpose_cast<<<dim3(HD / 32, DD / 32), tb, 0, stream>>>(Wv, WT + (size_t)4096 * 2048, DD, HD);

  // 8. ONE fused GEMM N=6144 (1536 tiles = 6/CU: barrier drains overlap across
  //    blocks, A-panels L2-shared) -> bf16 scan-layout q/k/v pre-activations
  gemm_qkv<<<dim3(6144 / 128, MM / 128), 256, 0, stream>>>(xb, WT, B1, B2, B3, MM, 6144, DD);

  // 9-11. convs (read bf16, write f32 scan layout). conv v runs last: its
  //    output vc overlays B1,B2 which convs q,k have already consumed.
  conv_silu_kernel<<<MM, 256, 0, stream>>>(B1, cq, qc, 1, 0.08838834764831845f);
  conv_silu_kernel<<<MM, 256, 0, stream>>>(B2, ck, kc, 1, 1.0f);
  conv_silu_kernel<<<MM, 256, 0, stream>>>(B3, cv, vc, 0, 1.0f);

  // 12. gate = x@Wg + bg -> bf16 row layout (over B3, consumed by conv v)
  transpose_cast<<<dim3(HD / 32, DD / 32), tb, 0, stream>>>(Wg, WT, DD, HD);
  gemm_bf16_bout<<<dim3(HD / 128, MM / 128), 256, 0, stream>>>(xb, WT, gateb, bg, MM, HD, DD);

  // 13. delta-rule scan (unchanged; o aliases v)
  scan_kernel<<<BB * HH * 8, 256, 0, stream>>>(qc, kc, vc, geb, betab, ob);

  // 14. gated RMSNorm -> bf16 (onb = xb, dead after gemms)
  out_norm_kernel<<<MM, 256, 0, stream>>>(ob, gateb, onw, onb);

  // 15. final projection
  transpose_cast<<<dim3(DD / 32, HD / 32), tb, 0, stream>>>(Wo, WT, HD, DD);
  gemm_bf16<<<dim3(DD / 128, MM / 128), 256, 0, stream>>>(onb, WT, out, nullptr, MM, DD, HD);
}